// Round 2
// baseline (2112.713 us; speedup 1.0000x reference)
//
#include <hip/hip_runtime.h>
#include <hip/hip_bf16.h>
#include <math.h>

#define Bq 16
#define Tq 256
#define Hq 512
#define Vq 32000
#define Gq 1536
#define NWG 16

typedef __attribute__((ext_vector_type(8))) short short8;
typedef __attribute__((ext_vector_type(4))) float f32x4;

__device__ __forceinline__ unsigned short f2bf(float f) {
    union { float f; unsigned int u; } v; v.f = f;
    unsigned int r = v.u + 0x7fffu + ((v.u >> 16) & 1u);
    return (unsigned short)(r >> 16);
}
__device__ __forceinline__ float bf2f(unsigned short h) {
    union { unsigned int u; float f; } v; v.u = ((unsigned int)h) << 16;
    return v.f;
}
__device__ __forceinline__ float sigm(float x) { return 1.0f / (1.0f + expf(-x)); }

// ---------------------------------------------------------------------------
// prep: cast E->bf16; split W_ih/W_hh into bf16 hi/lo pairs; reset barrier cnt
// ---------------------------------------------------------------------------
__global__ void prep_kernel(const float* __restrict__ E, const float* __restrict__ Wih,
                            const float* __restrict__ Whh,
                            unsigned short* __restrict__ Ebf,
                            unsigned short* __restrict__ WihHi, unsigned short* __restrict__ WihLo,
                            unsigned short* __restrict__ WhhHi, unsigned short* __restrict__ WhhLo,
                            int* __restrict__ cnt) {
    long tid = (long)blockIdx.x * blockDim.x + threadIdx.x;
    long stride = (long)gridDim.x * blockDim.x;
    for (long i = tid; i < (long)Vq * Hq; i += stride) Ebf[i] = f2bf(E[i]);
    for (long i = tid; i < (long)Gq * Hq; i += stride) {
        float w = Wih[i]; unsigned short hi = f2bf(w);
        WihHi[i] = hi; WihLo[i] = f2bf(w - bf2f(hi));
        w = Whh[i]; hi = f2bf(w);
        WhhHi[i] = hi; WhhLo[i] = f2bf(w - bf2f(hi));
    }
    if (tid == 0) *cnt = 0;
}

// ---------------------------------------------------------------------------
// gi: gi_all[t,b,:] = E[tok(t,b)] @ W_ih^T + b_ih   (split-bf16, ~fp32 faithful)
// grid (T, 16 col-blocks of 96), 384 threads = 6 waves, 1 16-col tile per wave
// ---------------------------------------------------------------------------
__launch_bounds__(384)
__global__ void gi_kernel(const int* __restrict__ target, const float* __restrict__ E,
                          const unsigned short* __restrict__ WihHi,
                          const unsigned short* __restrict__ WihLo,
                          const float* __restrict__ b_ih, float* __restrict__ gi_all) {
    __shared__ __align__(16) unsigned short Ahi[16][520];  // +8 pad: 2-way banks (free)
    __shared__ __align__(16) unsigned short Alo[16][520];
    __shared__ int toks[16];
    int t = blockIdx.x, gb = blockIdx.y;
    int tid = threadIdx.x;
    if (tid < 16) toks[tid] = (t == 0) ? 1 : target[tid * Tq + (t - 1)];  // START=1
    __syncthreads();
    for (int idx = tid; idx < 16 * Hq; idx += 384) {
        int r = idx >> 9, k = idx & 511;
        float v = E[(long)toks[r] * Hq + k];
        unsigned short hi = f2bf(v);
        Ahi[r][k] = hi; Alo[r][k] = f2bf(v - bf2f(hi));
    }
    __syncthreads();
    int wave = tid >> 6, lane = tid & 63;
    int gcb = gb * 96 + wave * 16;
    int row = lane & 15, kg = (lane >> 4) * 8;
    const unsigned short* bh = WihHi + (long)(gcb + row) * Hq;
    const unsigned short* bl = WihLo + (long)(gcb + row) * Hq;
    f32x4 aHH = {0,0,0,0}, aHL = {0,0,0,0}, aLH = {0,0,0,0};
#pragma unroll
    for (int ks = 0; ks < 16; ++ks) {
        int k0 = ks * 32 + kg;
        short8 ah = *(const short8*)&Ahi[row][k0];
        short8 al = *(const short8*)&Alo[row][k0];
        short8 wh = *(const short8*)&bh[k0];
        short8 wl = *(const short8*)&bl[k0];
        aHH = __builtin_amdgcn_mfma_f32_16x16x32_bf16(ah, wh, aHH, 0, 0, 0);
        aHL = __builtin_amdgcn_mfma_f32_16x16x32_bf16(ah, wl, aHL, 0, 0, 0);
        aLH = __builtin_amdgcn_mfma_f32_16x16x32_bf16(al, wh, aLH, 0, 0, 0);
    }
    int g = gcb + row;           // D: col = lane&15
    float bi = b_ih[g];
#pragma unroll
    for (int q = 0; q < 4; ++q) {
        int b = (lane >> 4) * 4 + q;   // D: row = (lane>>4)*4 + q
        gi_all[((long)(t * 16 + b)) * Gq + g] = aHH[q] + aHL[q] + aLH[q] + bi;
    }
}

// ---------------------------------------------------------------------------
// rnn: sequential GRU over 256 steps. 16 WGs, each owns 32 h-columns
// (96 gh-columns: r/z/n slices). W_hh frags preloaded in registers.
// Global spin barrier (monotonic counter, BOUNDED) per step.
// ---------------------------------------------------------------------------
__launch_bounds__(384, 1)
__global__ void rnn_kernel(const float* __restrict__ h0,
                           const unsigned short* __restrict__ WhhHi,
                           const unsigned short* __restrict__ WhhLo,
                           const float* __restrict__ b_hh, const float* __restrict__ gi_all,
                           float* __restrict__ H_all, unsigned short* __restrict__ H_bf,
                           int* cnt) {
    __shared__ __align__(16) unsigned short Ahi[16][520];
    __shared__ __align__(16) unsigned short Alo[16][520];
    __shared__ float gbuf[4][16][32];  // r_pre, z_pre, i_n, h_n
    int w = blockIdx.x, tid = threadIdx.x;
    int wave = tid >> 6, lane = tid & 63;
    int gate = wave >> 1;                            // 0:r 1:z 2:n
    int gcol = gate * 512 + w * 32 + (wave & 1) * 16;
    int row = lane & 15, kg = (lane >> 4) * 8;
    const unsigned short* bhp = WhhHi + (long)(gcol + row) * Hq;
    const unsigned short* blp = WhhLo + (long)(gcol + row) * Hq;
    short8 Bh[16], Bl[16];                           // stationary B frags: 128 VGPRs
#pragma unroll
    for (int ks = 0; ks < 16; ++ks) {
        Bh[ks] = *(const short8*)&bhp[ks * 32 + kg];
        Bl[ks] = *(const short8*)&blp[ks * 32 + kg];
    }
    float bhh = b_hh[gcol + row];
    for (int t = 0; t < Tq; ++t) {
        const float* src = (t == 0) ? h0 : (H_all + (long)(t - 1) * Bq * Hq);
        for (int idx = tid; idx < Bq * Hq; idx += 384) {
            float v = src[idx];
            unsigned short hi = f2bf(v);
            Ahi[idx >> 9][idx & 511] = hi;
            Alo[idx >> 9][idx & 511] = f2bf(v - bf2f(hi));
        }
        __syncthreads();
        f32x4 aHH = {0,0,0,0}, aHL = {0,0,0,0}, aLH = {0,0,0,0};
#pragma unroll
        for (int ks = 0; ks < 16; ++ks) {
            int k0 = ks * 32 + kg;
            short8 ah = *(const short8*)&Ahi[row][k0];
            short8 al = *(const short8*)&Alo[row][k0];
            aHH = __builtin_amdgcn_mfma_f32_16x16x32_bf16(ah, Bh[ks], aHH, 0, 0, 0);
            aHL = __builtin_amdgcn_mfma_f32_16x16x32_bf16(ah, Bl[ks], aHL, 0, 0, 0);
            aLH = __builtin_amdgcn_mfma_f32_16x16x32_bf16(al, Bh[ks], aLH, 0, 0, 0);
        }
        int jj = (wave & 1) * 16 + row;
#pragma unroll
        for (int q = 0; q < 4; ++q) {
            int b = (lane >> 4) * 4 + q;
            float ghv = aHH[q] + aHL[q] + aLH[q] + bhh;
            float giv = gi_all[((long)(t * 16 + b)) * Gq + (gcol + row)];
            if (gate < 2) gbuf[gate][b][jj] = ghv + giv;
            else { gbuf[2][b][jj] = giv; gbuf[3][b][jj] = ghv; }
        }
        __syncthreads();
        for (int idx = tid; idx < 512; idx += 384) {
            int b = idx >> 5, j2 = idx & 31;
            int jc = w * 32 + j2;
            float r = sigm(gbuf[0][b][j2]);
            float z = sigm(gbuf[1][b][j2]);
            float n = tanhf(gbuf[2][b][j2] + r * gbuf[3][b][j2]);
            float hp = bf2f(Ahi[b][jc]) + bf2f(Alo[b][jc]);   // ~exact h_prev
            float hn = (1.0f - z) * n + z * hp;
            H_all[(long)t * Bq * Hq + b * Hq + jc] = hn;
            H_bf[((long)(t * 16 + b)) * Hq + jc] = f2bf(hn);
        }
        __syncthreads();  // all waves drained vmcnt(0) here (HIP barrier semantics)
        if (tid == 0) {
            // agent-scope ACQ_REL RMW: release half writes back this XCD's L2
            // (incl. other threads' H_all stores, already drained by barrier);
            // acquire-load spin reads the device-coherent point.
            __hip_atomic_fetch_add(cnt, 1, __ATOMIC_ACQ_REL, __HIP_MEMORY_SCOPE_AGENT);
            int tgt = NWG * (t + 1);
            // BOUNDED spin: converts any pathological stall into a wrong
            // answer (with profile) instead of a container-killing hang.
            int guard = 0;
            while (__hip_atomic_load(cnt, __ATOMIC_ACQUIRE, __HIP_MEMORY_SCOPE_AGENT) < tgt
                   && guard < (1 << 18)) {
                __builtin_amdgcn_s_sleep(2);
                ++guard;
            }
        }
        __syncthreads();
    }
}

// ---------------------------------------------------------------------------
// logits: out[b,t,v] = H[t,b,:] @ E[v,:] + b_out[v]   (bf16 MFMA)
// 64x64 tile per WG, 4 waves; K-loop 16 x 32
// ---------------------------------------------------------------------------
__launch_bounds__(256)
__global__ void logits_kernel(const unsigned short* __restrict__ Hbf,
                              const unsigned short* __restrict__ Ebf,
                              const float* __restrict__ b_out, float* __restrict__ out) {
    __shared__ __align__(16) unsigned short Abuf[64][40];
    __shared__ __align__(16) unsigned short Bbuf[64][40];
    int bid = blockIdx.x;
    int nb = bid / 64, mb = bid % 64;   // M fastest: 64 M-blocks share each B-slice in L2
    int n0 = nb * 64, m0 = mb * 64;
    int tid = threadIdx.x;
    int wave = tid >> 6, lane = tid & 63;
    int row = lane & 15, kg = (lane >> 4) * 8;
    int sr = tid >> 2, sk = (tid & 3) * 8;
    f32x4 acc[4] = {{0,0,0,0},{0,0,0,0},{0,0,0,0},{0,0,0,0}};
    for (int kt = 0; kt < 16; ++kt) {
        int k0 = kt * 32;
        __syncthreads();
        *(short8*)&Abuf[sr][sk] = *(const short8*)&Hbf[(long)(m0 + sr) * Hq + k0 + sk];
        *(short8*)&Bbuf[sr][sk] = *(const short8*)&Ebf[(long)(n0 + sr) * Hq + k0 + sk];
        __syncthreads();
        short8 af = *(const short8*)&Abuf[wave * 16 + row][kg];
#pragma unroll
        for (int s = 0; s < 4; ++s) {
            short8 bfr = *(const short8*)&Bbuf[s * 16 + row][kg];
            acc[s] = __builtin_amdgcn_mfma_f32_16x16x32_bf16(af, bfr, acc[s], 0, 0, 0);
        }
    }
#pragma unroll
    for (int s = 0; s < 4; ++s) {
        int v = n0 + s * 16 + row;
        float bo = b_out[v];
#pragma unroll
        for (int q = 0; q < 4; ++q) {
            int m = m0 + wave * 16 + (lane >> 4) * 4 + q;
            int tt = m >> 4, bb = m & 15;   // m = t*16 + b
            out[((long)bb * Tq + tt) * Vq + v] = acc[s][q] + bo;
        }
    }
}

// ---------------------------------------------------------------------------
extern "C" void kernel_launch(void* const* d_in, const int* in_sizes, int n_in,
                              void* d_out, int out_size, void* d_ws, size_t ws_size,
                              hipStream_t stream) {
    const float* h0    = (const float*)d_in[0];
    const int*   target= (const int*)d_in[1];
    const float* E     = (const float*)d_in[2];
    const float* Wih   = (const float*)d_in[3];
    const float* Whh   = (const float*)d_in[4];
    const float* b_ih  = (const float*)d_in[5];
    const float* b_hh  = (const float*)d_in[6];
    const float* b_out = (const float*)d_in[7];
    float* out = (float*)d_out;

    char* ws = (char*)d_ws;
    size_t off = 0;
    unsigned short* Ebf   = (unsigned short*)(ws + off); off += (size_t)Vq * Hq * 2;  // 32.77 MB
    unsigned short* WihHi = (unsigned short*)(ws + off); off += (size_t)Gq * Hq * 2;
    unsigned short* WihLo = (unsigned short*)(ws + off); off += (size_t)Gq * Hq * 2;
    unsigned short* WhhHi = (unsigned short*)(ws + off); off += (size_t)Gq * Hq * 2;
    unsigned short* WhhLo = (unsigned short*)(ws + off); off += (size_t)Gq * Hq * 2;
    float*          gi_all= (float*)(ws + off);          off += (size_t)Tq * Bq * Gq * 4;  // 25.2 MB
    float*          H_all = (float*)(ws + off);          off += (size_t)Tq * Bq * Hq * 4;  // 8.4 MB
    unsigned short* Hbf   = (unsigned short*)(ws + off); off += (size_t)Tq * Bq * Hq * 2;  // 4.2 MB
    int*            cnt   = (int*)(ws + off);            off += 256;

    prep_kernel<<<dim3(2048), dim3(256), 0, stream>>>(E, Wih, Whh, Ebf, WihHi, WihLo,
                                                      WhhHi, WhhLo, cnt);
    gi_kernel<<<dim3(Tq, 16), dim3(384), 0, stream>>>(target, E, WihHi, WihLo, b_ih, gi_all);
    rnn_kernel<<<dim3(NWG), dim3(384), 0, stream>>>(h0, WhhHi, WhhLo, b_hh, gi_all,
                                                    H_all, Hbf, cnt);
    logits_kernel<<<dim3(500 * 64), dim3(256), 0, stream>>>(Hbf, Ebf, b_out, out);
}

// Round 3
// 1871.211 us; speedup vs baseline: 1.1291x; 1.1291x over previous
//
#include <hip/hip_runtime.h>
#include <hip/hip_bf16.h>
#include <math.h>

#define Bq 16
#define Tq 256
#define Hq 512
#define Vq 32000
#define Gq 1536
#define NWG 16

typedef __attribute__((ext_vector_type(8))) short short8;
typedef __attribute__((ext_vector_type(4))) float f32x4;

__device__ __forceinline__ unsigned short f2bf(float f) {
    union { float f; unsigned int u; } v; v.f = f;
    unsigned int r = v.u + 0x7fffu + ((v.u >> 16) & 1u);
    return (unsigned short)(r >> 16);
}
__device__ __forceinline__ float bf2f(unsigned short h) {
    union { unsigned int u; float f; } v; v.u = ((unsigned int)h) << 16;
    return v.f;
}
__device__ __forceinline__ float sigm(float x) { return 1.0f / (1.0f + expf(-x)); }

// ---------------------------------------------------------------------------
// prep: cast E->bf16; split W_ih/W_hh into bf16 hi/lo pairs; reset barrier cnt
// ---------------------------------------------------------------------------
__global__ void prep_kernel(const float* __restrict__ E, const float* __restrict__ Wih,
                            const float* __restrict__ Whh,
                            unsigned short* __restrict__ Ebf,
                            unsigned short* __restrict__ WihHi, unsigned short* __restrict__ WihLo,
                            unsigned short* __restrict__ WhhHi, unsigned short* __restrict__ WhhLo,
                            int* __restrict__ cnt) {
    long tid = (long)blockIdx.x * blockDim.x + threadIdx.x;
    long stride = (long)gridDim.x * blockDim.x;
    for (long i = tid; i < (long)Vq * Hq; i += stride) Ebf[i] = f2bf(E[i]);
    for (long i = tid; i < (long)Gq * Hq; i += stride) {
        float w = Wih[i]; unsigned short hi = f2bf(w);
        WihHi[i] = hi; WihLo[i] = f2bf(w - bf2f(hi));
        w = Whh[i]; hi = f2bf(w);
        WhhHi[i] = hi; WhhLo[i] = f2bf(w - bf2f(hi));
    }
    if (tid == 0) *cnt = 0;
}

// ---------------------------------------------------------------------------
// gi: gi_all[t,b,:] = E[tok(t,b)] @ W_ih^T + b_ih   (split-bf16, ~fp32 faithful)
// ---------------------------------------------------------------------------
__launch_bounds__(384)
__global__ void gi_kernel(const int* __restrict__ target, const float* __restrict__ E,
                          const unsigned short* __restrict__ WihHi,
                          const unsigned short* __restrict__ WihLo,
                          const float* __restrict__ b_ih, float* __restrict__ gi_all) {
    __shared__ __align__(16) unsigned short Ahi[16][520];
    __shared__ __align__(16) unsigned short Alo[16][520];
    __shared__ int toks[16];
    int t = blockIdx.x, gb = blockIdx.y;
    int tid = threadIdx.x;
    if (tid < 16) toks[tid] = (t == 0) ? 1 : target[tid * Tq + (t - 1)];  // START=1
    __syncthreads();
    for (int idx = tid; idx < 16 * Hq; idx += 384) {
        int r = idx >> 9, k = idx & 511;
        float v = E[(long)toks[r] * Hq + k];
        unsigned short hi = f2bf(v);
        Ahi[r][k] = hi; Alo[r][k] = f2bf(v - bf2f(hi));
    }
    __syncthreads();
    int wave = tid >> 6, lane = tid & 63;
    int gcb = gb * 96 + wave * 16;
    int row = lane & 15, kg = (lane >> 4) * 8;
    const unsigned short* bh = WihHi + (long)(gcb + row) * Hq;
    const unsigned short* bl = WihLo + (long)(gcb + row) * Hq;
    f32x4 aHH = {0,0,0,0}, aHL = {0,0,0,0}, aLH = {0,0,0,0};
#pragma unroll
    for (int ks = 0; ks < 16; ++ks) {
        int k0 = ks * 32 + kg;
        short8 ah = *(const short8*)&Ahi[row][k0];
        short8 al = *(const short8*)&Alo[row][k0];
        short8 wh = *(const short8*)&bh[k0];
        short8 wl = *(const short8*)&bl[k0];
        aHH = __builtin_amdgcn_mfma_f32_16x16x32_bf16(ah, wh, aHH, 0, 0, 0);
        aHL = __builtin_amdgcn_mfma_f32_16x16x32_bf16(ah, wl, aHL, 0, 0, 0);
        aLH = __builtin_amdgcn_mfma_f32_16x16x32_bf16(al, wh, aLH, 0, 0, 0);
    }
    int g = gcb + row;
    float bi = b_ih[g];
#pragma unroll
    for (int q = 0; q < 4; ++q) {
        int b = (lane >> 4) * 4 + q;
        gi_all[((long)(t * 16 + b)) * Gq + g] = aHH[q] + aHL[q] + aLH[q] + bi;
    }
}

// ---------------------------------------------------------------------------
// rnn: 16 WGs, 256 sequential steps. Cross-WG h exchange via RELAXED
// agent-scope atomics (sc0/sc1 coherent ops, NO L2 wb/inv per step).
// h packed as (hi<<16|lo) bf16 pairs in u64 words.
// ---------------------------------------------------------------------------
__launch_bounds__(384, 1)
__global__ void rnn_kernel(const float* __restrict__ h0,
                           const unsigned short* __restrict__ WhhHi,
                           const unsigned short* __restrict__ WhhLo,
                           const float* __restrict__ b_hh, const float* __restrict__ gi_all,
                           unsigned long long* Hpk, unsigned short* __restrict__ H_bf,
                           int* cnt) {
    __shared__ __align__(16) unsigned short Ahi[16][520];
    __shared__ __align__(16) unsigned short Alo[16][520];
    __shared__ float gbuf[4][16][33];  // r_pre, z_pre, i_n, h_n (+1 pad)
    int w = blockIdx.x, tid = threadIdx.x;
    int wave = tid >> 6, lane = tid & 63;
    int gate = wave >> 1;                            // 0:r 1:z 2:n
    int gcol = gate * 512 + w * 32 + (wave & 1) * 16;
    int row = lane & 15, kg = (lane >> 4) * 8;
    const unsigned short* bhp = WhhHi + (long)(gcol + row) * Hq;
    const unsigned short* blp = WhhLo + (long)(gcol + row) * Hq;
    short8 Bh[16], Bl[16];                           // stationary W_hh frags
#pragma unroll
    for (int ks = 0; ks < 16; ++ks) {
        Bh[ks] = *(const short8*)&bhp[ks * 32 + kg];
        Bl[ks] = *(const short8*)&blp[ks * 32 + kg];
    }
    float bhh = b_hh[gcol + row];
    // gi register prefetch (step 0)
    float gin[4];
#pragma unroll
    for (int q = 0; q < 4; ++q) {
        int b = (lane >> 4) * 4 + q;
        gin[q] = gi_all[(long)b * Gq + (gcol + row)];
    }
    for (int t = 0; t < Tq; ++t) {
        // ---- stage h_prev into LDS as bf16 hi/lo ----
        if (t == 0) {
            for (int idx = tid; idx < Bq * Hq; idx += 384) {
                float v = h0[idx];
                unsigned short hi = f2bf(v);
                Ahi[idx >> 9][idx & 511] = hi;
                Alo[idx >> 9][idx & 511] = f2bf(v - bf2f(hi));
            }
        } else {
            const unsigned long long* src = Hpk + (long)(t - 1) * 4096;
            for (int p = tid; p < 4096; p += 384) {
                unsigned long long v = __hip_atomic_load(&src[p], __ATOMIC_RELAXED,
                                                         __HIP_MEMORY_SCOPE_AGENT);
                unsigned int e0 = (unsigned int)v, e1 = (unsigned int)(v >> 32);
                int b = p >> 8, j = (p & 255) * 2;
                *(unsigned int*)&Ahi[b][j] = (e0 >> 16) | (e1 & 0xFFFF0000u);
                *(unsigned int*)&Alo[b][j] = (e0 & 0xFFFFu) | (e1 << 16);
            }
        }
        __syncthreads();
        // ---- gh = h @ Whh^T (split-bf16, 3 MFMA per k-slice) ----
        f32x4 aHH = {0,0,0,0}, aHL = {0,0,0,0}, aLH = {0,0,0,0};
#pragma unroll
        for (int ks = 0; ks < 16; ++ks) {
            int k0 = ks * 32 + kg;
            short8 ah = *(const short8*)&Ahi[row][k0];
            short8 al = *(const short8*)&Alo[row][k0];
            aHH = __builtin_amdgcn_mfma_f32_16x16x32_bf16(ah, Bh[ks], aHH, 0, 0, 0);
            aHL = __builtin_amdgcn_mfma_f32_16x16x32_bf16(ah, Bl[ks], aHL, 0, 0, 0);
            aLH = __builtin_amdgcn_mfma_f32_16x16x32_bf16(al, Bh[ks], aLH, 0, 0, 0);
        }
        int jj = (wave & 1) * 16 + row;
#pragma unroll
        for (int q = 0; q < 4; ++q) {
            int b = (lane >> 4) * 4 + q;
            float ghv = aHH[q] + aHL[q] + aLH[q] + bhh;
            if (gate < 2) gbuf[gate][b][jj] = ghv + gin[q];
            else { gbuf[2][b][jj] = gin[q]; gbuf[3][b][jj] = ghv; }
        }
        __syncthreads();
        // ---- gates + h_new, coherent store (pairs) ----
        for (int p = tid; p < 256; p += 384) {
            int b = p >> 4, jp = p & 15;
            int j0 = jp * 2, j1 = j0 + 1;
            int jc0 = w * 32 + j0;
            float r0 = sigm(gbuf[0][b][j0]);
            float z0 = sigm(gbuf[1][b][j0]);
            float n0 = tanhf(gbuf[2][b][j0] + r0 * gbuf[3][b][j0]);
            float hp0 = bf2f(Ahi[b][jc0]) + bf2f(Alo[b][jc0]);
            float hn0 = (1.0f - z0) * n0 + z0 * hp0;
            float r1 = sigm(gbuf[0][b][j1]);
            float z1 = sigm(gbuf[1][b][j1]);
            float n1 = tanhf(gbuf[2][b][j1] + r1 * gbuf[3][b][j1]);
            float hp1 = bf2f(Ahi[b][jc0 + 1]) + bf2f(Alo[b][jc0 + 1]);
            float hn1 = (1.0f - z1) * n1 + z1 * hp1;
            unsigned short h0h = f2bf(hn0), h1h = f2bf(hn1);
            unsigned short h0l = f2bf(hn0 - bf2f(h0h)), h1l = f2bf(hn1 - bf2f(h1h));
            unsigned int e0 = ((unsigned int)h0h << 16) | h0l;
            unsigned int e1 = ((unsigned int)h1h << 16) | h1l;
            __hip_atomic_store(&Hpk[(long)t * 4096 + b * 256 + w * 16 + jp],
                               ((unsigned long long)e1 << 32) | e0,
                               __ATOMIC_RELAXED, __HIP_MEMORY_SCOPE_AGENT);
            // bf16 h for logits GEMM (cached path; kernel-boundary flush)
            *(unsigned int*)&H_bf[((long)(t * 16 + b)) * Hq + jc0] =
                ((unsigned int)h1h << 16) | h0h;
        }
        __syncthreads();  // every wave drains vmcnt(0) -> coherent stores at LLC
        // ---- gi prefetch for t+1 (in flight across the spin) ----
        int tp = (t + 1 < Tq) ? (t + 1) : t;
#pragma unroll
        for (int q = 0; q < 4; ++q) {
            int b = (lane >> 4) * 4 + q;
            gin[q] = gi_all[((long)(tp * 16 + b)) * Gq + (gcol + row)];
        }
        // ---- global step barrier: relaxed arrive + bounded relaxed spin ----
        if (tid == 0) {
            __hip_atomic_fetch_add(cnt, 1, __ATOMIC_RELAXED, __HIP_MEMORY_SCOPE_AGENT);
            int tgt = NWG * (t + 1);
            int guard = 0;
            while (__hip_atomic_load(cnt, __ATOMIC_RELAXED, __HIP_MEMORY_SCOPE_AGENT) < tgt
                   && guard < (1 << 15)) {
                __builtin_amdgcn_s_sleep(2);
                ++guard;
            }
        }
        __syncthreads();
    }
}

// ---------------------------------------------------------------------------
// logits: out[b,t,v] = H[t,b,:] @ E[v,:] + b_out[v]   (bf16 MFMA)
// ---------------------------------------------------------------------------
__launch_bounds__(256)
__global__ void logits_kernel(const unsigned short* __restrict__ Hbf,
                              const unsigned short* __restrict__ Ebf,
                              const float* __restrict__ b_out, float* __restrict__ out) {
    __shared__ __align__(16) unsigned short Abuf[64][40];
    __shared__ __align__(16) unsigned short Bbuf[64][40];
    int bid = blockIdx.x;
    int nb = bid / 64, mb = bid % 64;
    int n0 = nb * 64, m0 = mb * 64;
    int tid = threadIdx.x;
    int wave = tid >> 6, lane = tid & 63;
    int row = lane & 15, kg = (lane >> 4) * 8;
    int sr = tid >> 2, sk = (tid & 3) * 8;
    f32x4 acc[4] = {{0,0,0,0},{0,0,0,0},{0,0,0,0},{0,0,0,0}};
    for (int kt = 0; kt < 16; ++kt) {
        int k0 = kt * 32;
        __syncthreads();
        *(short8*)&Abuf[sr][sk] = *(const short8*)&Hbf[(long)(m0 + sr) * Hq + k0 + sk];
        *(short8*)&Bbuf[sr][sk] = *(const short8*)&Ebf[(long)(n0 + sr) * Hq + k0 + sk];
        __syncthreads();
        short8 af = *(const short8*)&Abuf[wave * 16 + row][kg];
#pragma unroll
        for (int s = 0; s < 4; ++s) {
            short8 bfr = *(const short8*)&Bbuf[s * 16 + row][kg];
            acc[s] = __builtin_amdgcn_mfma_f32_16x16x32_bf16(af, bfr, acc[s], 0, 0, 0);
        }
    }
#pragma unroll
    for (int s = 0; s < 4; ++s) {
        int v = n0 + s * 16 + row;
        float bo = b_out[v];
#pragma unroll
        for (int q = 0; q < 4; ++q) {
            int m = m0 + wave * 16 + (lane >> 4) * 4 + q;
            int tt = m >> 4, bb = m & 15;   // m = t*16 + b
            out[((long)bb * Tq + tt) * Vq + v] = acc[s][q] + bo;
        }
    }
}

// ---------------------------------------------------------------------------
extern "C" void kernel_launch(void* const* d_in, const int* in_sizes, int n_in,
                              void* d_out, int out_size, void* d_ws, size_t ws_size,
                              hipStream_t stream) {
    const float* h0    = (const float*)d_in[0];
    const int*   target= (const int*)d_in[1];
    const float* E     = (const float*)d_in[2];
    const float* Wih   = (const float*)d_in[3];
    const float* Whh   = (const float*)d_in[4];
    const float* b_ih  = (const float*)d_in[5];
    const float* b_hh  = (const float*)d_in[6];
    const float* b_out = (const float*)d_in[7];
    float* out = (float*)d_out;

    char* ws = (char*)d_ws;
    size_t off = 0;
    unsigned short* Ebf   = (unsigned short*)(ws + off); off += (size_t)Vq * Hq * 2;
    unsigned short* WihHi = (unsigned short*)(ws + off); off += (size_t)Gq * Hq * 2;
    unsigned short* WihLo = (unsigned short*)(ws + off); off += (size_t)Gq * Hq * 2;
    unsigned short* WhhHi = (unsigned short*)(ws + off); off += (size_t)Gq * Hq * 2;
    unsigned short* WhhLo = (unsigned short*)(ws + off); off += (size_t)Gq * Hq * 2;
    float*          gi_all= (float*)(ws + off);          off += (size_t)Tq * Bq * Gq * 4;
    unsigned long long* Hpk = (unsigned long long*)(ws + off); off += (size_t)Tq * 4096 * 8;
    unsigned short* Hbf   = (unsigned short*)(ws + off); off += (size_t)Tq * Bq * Hq * 2;
    int*            cnt   = (int*)(ws + off);            off += 256;

    prep_kernel<<<dim3(2048), dim3(256), 0, stream>>>(E, Wih, Whh, Ebf, WihHi, WihLo,
                                                      WhhHi, WhhLo, cnt);
    gi_kernel<<<dim3(Tq, 16), dim3(384), 0, stream>>>(target, E, WihHi, WihLo, b_ih, gi_all);
    rnn_kernel<<<dim3(NWG), dim3(384), 0, stream>>>(h0, WhhHi, WhhLo, b_hh, gi_all,
                                                    Hpk, Hbf, cnt);
    logits_kernel<<<dim3(500 * 64), dim3(256), 0, stream>>>(Hbf, Ebf, b_out, out);
}

// Round 4
// 1336.957 us; speedup vs baseline: 1.5802x; 1.3996x over previous
//
#include <hip/hip_runtime.h>
#include <hip/hip_bf16.h>
#include <math.h>

#define Bq 16
#define Tq 256
#define Hq 512
#define Vq 32000
#define Gq 1536
#define NWG 16

typedef __attribute__((ext_vector_type(8))) short short8;
typedef __attribute__((ext_vector_type(4))) float f32x4;

typedef const __attribute__((address_space(1))) void g_void;
typedef __attribute__((address_space(3))) void l_void;

__device__ __forceinline__ unsigned short f2bf(float f) {
    union { float f; unsigned int u; } v; v.f = f;
    unsigned int r = v.u + 0x7fffu + ((v.u >> 16) & 1u);
    return (unsigned short)(r >> 16);
}
__device__ __forceinline__ float bf2f(unsigned short h) {
    union { unsigned int u; float f; } v; v.u = ((unsigned int)h) << 16;
    return v.f;
}
__device__ __forceinline__ float sigm(float x) { return 1.0f / (1.0f + expf(-x)); }

// ---------------------------------------------------------------------------
// prep: cast E->bf16; split W_ih/W_hh into bf16 hi/lo pairs; reset flags
// ---------------------------------------------------------------------------
__global__ void prep_kernel(const float* __restrict__ E, const float* __restrict__ Wih,
                            const float* __restrict__ Whh,
                            unsigned short* __restrict__ Ebf,
                            unsigned short* __restrict__ WihHi, unsigned short* __restrict__ WihLo,
                            unsigned short* __restrict__ WhhHi, unsigned short* __restrict__ WhhLo,
                            int* __restrict__ flags) {
    long tid = (long)blockIdx.x * blockDim.x + threadIdx.x;
    long stride = (long)gridDim.x * blockDim.x;
    for (long i = tid; i < (long)Vq * Hq; i += stride) Ebf[i] = f2bf(E[i]);
    for (long i = tid; i < (long)Gq * Hq; i += stride) {
        float w = Wih[i]; unsigned short hi = f2bf(w);
        WihHi[i] = hi; WihLo[i] = f2bf(w - bf2f(hi));
        w = Whh[i]; hi = f2bf(w);
        WhhHi[i] = hi; WhhLo[i] = f2bf(w - bf2f(hi));
    }
    if (tid < 512) flags[tid] = 0;   // 16 flag slots, 128B apart (reset every launch)
}

// ---------------------------------------------------------------------------
// gi: gi_all[t,b,:] = E[tok(t,b)] @ W_ih^T + b_ih   (split-bf16, ~fp32 faithful)
// ---------------------------------------------------------------------------
__launch_bounds__(384)
__global__ void gi_kernel(const int* __restrict__ target, const float* __restrict__ E,
                          const unsigned short* __restrict__ WihHi,
                          const unsigned short* __restrict__ WihLo,
                          const float* __restrict__ b_ih, float* __restrict__ gi_all) {
    __shared__ __align__(16) unsigned short Ahi[16][520];
    __shared__ __align__(16) unsigned short Alo[16][520];
    __shared__ int toks[16];
    int t = blockIdx.x, gb = blockIdx.y;
    int tid = threadIdx.x;
    if (tid < 16) toks[tid] = (t == 0) ? 1 : target[tid * Tq + (t - 1)];  // START=1
    __syncthreads();
    for (int idx = tid; idx < 16 * Hq; idx += 384) {
        int r = idx >> 9, k = idx & 511;
        float v = E[(long)toks[r] * Hq + k];
        unsigned short hi = f2bf(v);
        Ahi[r][k] = hi; Alo[r][k] = f2bf(v - bf2f(hi));
    }
    __syncthreads();
    int wave = tid >> 6, lane = tid & 63;
    int gcb = gb * 96 + wave * 16;
    int row = lane & 15, kg = (lane >> 4) * 8;
    const unsigned short* bh = WihHi + (long)(gcb + row) * Hq;
    const unsigned short* bl = WihLo + (long)(gcb + row) * Hq;
    f32x4 aHH = {0,0,0,0}, aHL = {0,0,0,0}, aLH = {0,0,0,0};
#pragma unroll
    for (int ks = 0; ks < 16; ++ks) {
        int k0 = ks * 32 + kg;
        short8 ah = *(const short8*)&Ahi[row][k0];
        short8 al = *(const short8*)&Alo[row][k0];
        short8 wh = *(const short8*)&bh[k0];
        short8 wl = *(const short8*)&bl[k0];
        aHH = __builtin_amdgcn_mfma_f32_16x16x32_bf16(ah, wh, aHH, 0, 0, 0);
        aHL = __builtin_amdgcn_mfma_f32_16x16x32_bf16(ah, wl, aHL, 0, 0, 0);
        aLH = __builtin_amdgcn_mfma_f32_16x16x32_bf16(al, wh, aLH, 0, 0, 0);
    }
    int g = gcb + row;
    float bi = b_ih[g];
#pragma unroll
    for (int q = 0; q < 4; ++q) {
        int b = (lane >> 4) * 4 + q;
        gi_all[((long)(t * 16 + b)) * Gq + g] = aHH[q] + aHL[q] + aLH[q] + bi;
    }
}

// ---------------------------------------------------------------------------
// rnn: 16 WGs, 256 sequential steps. h exchange via relaxed agent-scope
// atomics. Flag-broadcast barrier (per-WG flag word, all-wave ballot spin).
// Batched (unrolled) coherent loads: one RTT instead of ~11.
// ---------------------------------------------------------------------------
__launch_bounds__(384, 1)
__global__ void rnn_kernel(const float* __restrict__ h0,
                           const unsigned short* __restrict__ WhhHi,
                           const unsigned short* __restrict__ WhhLo,
                           const float* __restrict__ b_hh, const float* __restrict__ gi_all,
                           unsigned long long* Hpk, unsigned short* __restrict__ H_bf,
                           int* flags) {
    __shared__ __align__(16) unsigned short Ahi[16][520];
    __shared__ __align__(16) unsigned short Alo[16][520];
    __shared__ float gbuf[4][16][33];  // r_pre, z_pre, i_n, h_n
    int w = blockIdx.x, tid = threadIdx.x;
    int wave = tid >> 6, lane = tid & 63;
    int gate = wave >> 1;                            // 0:r 1:z 2:n
    int gcol = gate * 512 + w * 32 + (wave & 1) * 16;
    int row = lane & 15, kg = (lane >> 4) * 8;
    const unsigned short* bhp = WhhHi + (long)(gcol + row) * Hq;
    const unsigned short* blp = WhhLo + (long)(gcol + row) * Hq;
    short8 Bh[16], Bl[16];                           // stationary W_hh frags
#pragma unroll
    for (int ks = 0; ks < 16; ++ks) {
        Bh[ks] = *(const short8*)&bhp[ks * 32 + kg];
        Bl[ks] = *(const short8*)&blp[ks * 32 + kg];
    }
    float bhh = b_hh[gcol + row];
    float gin[4];
#pragma unroll
    for (int q = 0; q < 4; ++q) {
        int b = (lane >> 4) * 4 + q;
        gin[q] = gi_all[(long)b * Gq + (gcol + row)];
    }
    int flo = (lane & 15) * 32;   // each lane polls one WG's flag word
    for (int t = 0; t < Tq; ++t) {
        // ---- wait for h_{t-1}, then batched coherent load -> LDS ----
        if (t == 0) {
            for (int idx = tid; idx < Bq * Hq; idx += 384) {
                float v = h0[idx];
                unsigned short hi = f2bf(v);
                Ahi[idx >> 9][idx & 511] = hi;
                Alo[idx >> 9][idx & 511] = f2bf(v - bf2f(hi));
            }
        } else {
            int guard = 0;
            while (guard < (1 << 15)) {   // bounded: hang -> wrong answer, not dead pod
                int fv = __hip_atomic_load(&flags[flo], __ATOMIC_RELAXED,
                                           __HIP_MEMORY_SCOPE_AGENT);
                if (__all(fv >= t)) break;
                __builtin_amdgcn_s_sleep(1);
                ++guard;
            }
            asm volatile("" ::: "memory");  // no code motion across the spin
            const unsigned long long* src = Hpk + (long)(t - 1) * 4096;
            unsigned long long vb[11];
#pragma unroll
            for (int i = 0; i < 10; ++i)
                vb[i] = __hip_atomic_load(&src[tid + i * 384], __ATOMIC_RELAXED,
                                          __HIP_MEMORY_SCOPE_AGENT);
            if (tid < 256)
                vb[10] = __hip_atomic_load(&src[tid + 3840], __ATOMIC_RELAXED,
                                           __HIP_MEMORY_SCOPE_AGENT);
#pragma unroll
            for (int i = 0; i < 10; ++i) {
                int p = tid + i * 384;
                unsigned int e0 = (unsigned int)vb[i], e1 = (unsigned int)(vb[i] >> 32);
                int b = p >> 8, j = (p & 255) * 2;
                *(unsigned int*)&Ahi[b][j] = (e0 >> 16) | (e1 & 0xFFFF0000u);
                *(unsigned int*)&Alo[b][j] = (e0 & 0xFFFFu) | (e1 << 16);
            }
            if (tid < 256) {
                int p = tid + 3840;
                unsigned int e0 = (unsigned int)vb[10], e1 = (unsigned int)(vb[10] >> 32);
                int b = p >> 8, j = (p & 255) * 2;
                *(unsigned int*)&Ahi[b][j] = (e0 >> 16) | (e1 & 0xFFFF0000u);
                *(unsigned int*)&Alo[b][j] = (e0 & 0xFFFFu) | (e1 << 16);
            }
        }
        __syncthreads();
        // ---- gh = h @ Whh^T: split-bf16, 6 independent MFMA chains ----
        f32x4 xHH = {0,0,0,0}, xHL = {0,0,0,0}, xLH = {0,0,0,0};
        f32x4 yHH = {0,0,0,0}, yHL = {0,0,0,0}, yLH = {0,0,0,0};
#pragma unroll
        for (int ks = 0; ks < 8; ++ks) {
            int k0 = ks * 32 + kg;
            short8 ah = *(const short8*)&Ahi[row][k0];
            short8 al = *(const short8*)&Alo[row][k0];
            xHH = __builtin_amdgcn_mfma_f32_16x16x32_bf16(ah, Bh[ks], xHH, 0, 0, 0);
            xHL = __builtin_amdgcn_mfma_f32_16x16x32_bf16(ah, Bl[ks], xHL, 0, 0, 0);
            xLH = __builtin_amdgcn_mfma_f32_16x16x32_bf16(al, Bh[ks], xLH, 0, 0, 0);
        }
#pragma unroll
        for (int ks = 8; ks < 16; ++ks) {
            int k0 = ks * 32 + kg;
            short8 ah = *(const short8*)&Ahi[row][k0];
            short8 al = *(const short8*)&Alo[row][k0];
            yHH = __builtin_amdgcn_mfma_f32_16x16x32_bf16(ah, Bh[ks], yHH, 0, 0, 0);
            yHL = __builtin_amdgcn_mfma_f32_16x16x32_bf16(ah, Bl[ks], yHL, 0, 0, 0);
            yLH = __builtin_amdgcn_mfma_f32_16x16x32_bf16(al, Bh[ks], yLH, 0, 0, 0);
        }
        int jj = (wave & 1) * 16 + row;
#pragma unroll
        for (int q = 0; q < 4; ++q) {
            int b = (lane >> 4) * 4 + q;
            float ghv = (xHH[q] + yHH[q]) + (xHL[q] + yHL[q]) + (xLH[q] + yLH[q]) + bhh;
            if (gate < 2) gbuf[gate][b][jj] = ghv + gin[q];
            else { gbuf[2][b][jj] = gin[q]; gbuf[3][b][jj] = ghv; }
        }
        __syncthreads();
        // ---- gates + h_new, coherent store ----
        if (tid < 256) {
            int b = tid >> 4, jp = tid & 15;
            int j0 = jp * 2, j1 = j0 + 1;
            int jc0 = w * 32 + j0;
            float r0 = sigm(gbuf[0][b][j0]);
            float z0 = sigm(gbuf[1][b][j0]);
            float n0 = tanhf(gbuf[2][b][j0] + r0 * gbuf[3][b][j0]);
            float hp0 = bf2f(Ahi[b][jc0]) + bf2f(Alo[b][jc0]);
            float hn0 = (1.0f - z0) * n0 + z0 * hp0;
            float r1 = sigm(gbuf[0][b][j1]);
            float z1 = sigm(gbuf[1][b][j1]);
            float n1 = tanhf(gbuf[2][b][j1] + r1 * gbuf[3][b][j1]);
            float hp1 = bf2f(Ahi[b][jc0 + 1]) + bf2f(Alo[b][jc0 + 1]);
            float hn1 = (1.0f - z1) * n1 + z1 * hp1;
            unsigned short h0h = f2bf(hn0), h1h = f2bf(hn1);
            unsigned short h0l = f2bf(hn0 - bf2f(h0h)), h1l = f2bf(hn1 - bf2f(h1h));
            unsigned int e0 = ((unsigned int)h0h << 16) | h0l;
            unsigned int e1 = ((unsigned int)h1h << 16) | h1l;
            __hip_atomic_store(&Hpk[(long)t * 4096 + b * 256 + w * 16 + jp],
                               ((unsigned long long)e1 << 32) | e0,
                               __ATOMIC_RELAXED, __HIP_MEMORY_SCOPE_AGENT);
            *(unsigned int*)&H_bf[((long)(t * 16 + b)) * Hq + jc0] =
                ((unsigned int)h1h << 16) | h0h;
        }
        __syncthreads();  // all waves drain vmcnt(0): h stores at coherent point
        // gi prefetch for t+1 rides across the flag store + next spin
        int tp = (t + 1 < Tq) ? (t + 1) : t;
#pragma unroll
        for (int q = 0; q < 4; ++q) {
            int b = (lane >> 4) * 4 + q;
            gin[q] = gi_all[((long)(tp * 16 + b)) * Gq + (gcol + row)];
        }
        if (tid == 0)
            __hip_atomic_store(&flags[w * 32], t + 1, __ATOMIC_RELAXED,
                               __HIP_MEMORY_SCOPE_AGENT);
    }
}

// ---------------------------------------------------------------------------
// logits: out[b,t,v] = H[t,b,:] @ E[v,:] + b_out[v]
// m97 structure: 128x128 tile, BK=64, global_load_lds w16, XOR-swizzled LDS
// (pre-swizzled global source, rule #21), 4 waves each 64x64, 32 MFMA/K-step.
// ---------------------------------------------------------------------------
__launch_bounds__(256)
__global__ void logits_kernel(const unsigned short* __restrict__ Hbf,
                              const unsigned short* __restrict__ Ebf,
                              const float* __restrict__ b_out, float* __restrict__ out) {
    __shared__ __align__(16) unsigned short As[128 * 64];
    __shared__ __align__(16) unsigned short Bs[128 * 64];
    int bid = blockIdx.x;
    int mb = bid & 31, nb = bid >> 5;     // M fastest: 32 mb-blocks share E-slice in L2
    int m0 = mb * 128, n0 = nb * 128;
    int tid = threadIdx.x;
    int wid = tid >> 6, lane = tid & 63;
    int wr = wid >> 1, wc = wid & 1;       // 2x2 wave grid, 64x64 per wave
    // staging source (pre-swizzled): LDS row r gets global slot (lane&7)^(r&7)
    int rA = lane >> 3;                    // r&7 == lane>>3 for every issue
    int slp = (lane & 7) ^ rA;
    const unsigned short* gA = Hbf + (long)(m0 + wid * 8 + rA) * Hq + slp * 8;
    const unsigned short* gB = Ebf + (long)(n0 + wid * 8 + rA) * Hq + slp * 8;
    unsigned short* ldsA = As + wid * 512;   // +issue*2048 (bytes: wid*1024+issue*4096)
    unsigned short* ldsB = Bs + wid * 512;
    // fragment read bases
    int fr = lane & 15, r7 = lane & 7, sb = lane >> 4;
    int Ra = wr * 64 + fr, Rb = wc * 64 + fr;
    f32x4 acc[4][4] = {};
    for (int kt = 0; kt < 8; ++kt) {
        if (kt) __syncthreads();
        int ko = kt * 64;
#pragma unroll
        for (int i = 0; i < 4; ++i) {
            __builtin_amdgcn_global_load_lds((g_void*)(gA + (long)i * 32 * Hq + ko),
                                             (l_void*)(ldsA + i * 2048), 16, 0, 0);
            __builtin_amdgcn_global_load_lds((g_void*)(gB + (long)i * 32 * Hq + ko),
                                             (l_void*)(ldsB + i * 2048), 16, 0, 0);
        }
        __syncthreads();   // barrier drains vmcnt(0): LDS ready
#pragma unroll
        for (int ks = 0; ks < 2; ++ks) {
            short8 af[4], bf[4];
#pragma unroll
            for (int f = 0; f < 4; ++f) {
                int Rr = Ra + f * 16;
                af[f] = *(const short8*)&As[Rr * 64 + (((sb + ks * 4) ^ r7) << 3)];
                int Rc = Rb + f * 16;
                bf[f] = *(const short8*)&Bs[Rc * 64 + (((sb + ks * 4) ^ r7) << 3)];
            }
#pragma unroll
            for (int fm = 0; fm < 4; ++fm)
#pragma unroll
                for (int fn = 0; fn < 4; ++fn)
                    acc[fm][fn] = __builtin_amdgcn_mfma_f32_16x16x32_bf16(
                        af[fm], bf[fn], acc[fm][fn], 0, 0, 0);
        }
    }
#pragma unroll
    for (int fn = 0; fn < 4; ++fn) {
        int v = n0 + wc * 64 + fn * 16 + fr;
        float bo = b_out[v];
#pragma unroll
        for (int fm = 0; fm < 4; ++fm) {
#pragma unroll
            for (int q = 0; q < 4; ++q) {
                int m = m0 + wr * 64 + fm * 16 + (lane >> 4) * 4 + q;
                out[((long)(m & 15) * Tq + (m >> 4)) * Vq + v] = acc[fm][fn][q] + bo;
            }
        }
    }
}

// ---------------------------------------------------------------------------
extern "C" void kernel_launch(void* const* d_in, const int* in_sizes, int n_in,
                              void* d_out, int out_size, void* d_ws, size_t ws_size,
                              hipStream_t stream) {
    const float* h0    = (const float*)d_in[0];
    const int*   target= (const int*)d_in[1];
    const float* E     = (const float*)d_in[2];
    const float* Wih   = (const float*)d_in[3];
    const float* Whh   = (const float*)d_in[4];
    const float* b_ih  = (const float*)d_in[5];
    const float* b_hh  = (const float*)d_in[6];
    const float* b_out = (const float*)d_in[7];
    float* out = (float*)d_out;

    char* ws = (char*)d_ws;
    size_t off = 0;
    unsigned short* Ebf   = (unsigned short*)(ws + off); off += (size_t)Vq * Hq * 2;
    unsigned short* WihHi = (unsigned short*)(ws + off); off += (size_t)Gq * Hq * 2;
    unsigned short* WihLo = (unsigned short*)(ws + off); off += (size_t)Gq * Hq * 2;
    unsigned short* WhhHi = (unsigned short*)(ws + off); off += (size_t)Gq * Hq * 2;
    unsigned short* WhhLo = (unsigned short*)(ws + off); off += (size_t)Gq * Hq * 2;
    float*          gi_all= (float*)(ws + off);          off += (size_t)Tq * Bq * Gq * 4;
    unsigned long long* Hpk = (unsigned long long*)(ws + off); off += (size_t)Tq * 4096 * 8;
    unsigned short* Hbf   = (unsigned short*)(ws + off); off += (size_t)Tq * Bq * Hq * 2;
    int*            flags = (int*)(ws + off);            off += 512 * 4;

    prep_kernel<<<dim3(2048), dim3(256), 0, stream>>>(E, Wih, Whh, Ebf, WihHi, WihLo,
                                                      WhhHi, WhhLo, flags);
    gi_kernel<<<dim3(Tq, 16), dim3(384), 0, stream>>>(target, E, WihHi, WihLo, b_ih, gi_all);
    rnn_kernel<<<dim3(NWG), dim3(384), 0, stream>>>(h0, WhhHi, WhhLo, b_hh, gi_all,
                                                    Hpk, Hbf, flags);
    logits_kernel<<<dim3(32 * 250), dim3(256), 0, stream>>>(Hbf, Ebf, b_out, out);
}